// Round 2
// baseline (2066.934 us; speedup 1.0000x reference)
//
#include <hip/hip_runtime.h>
#include <cstdint>
#include <cmath>

#define HWSZ    15000      // H*W = 100*150
#define W_FEAT  150
#define A_NUM   9
#define NPER    135000     // A_NUM * HWSZ
#define B_NUM   16
#define PRE_NMS 6000
#define POST_NMS 300
#define NBINS   16384      // top-14-bit histogram
#define CAND_CAP 8192

// 9 base anchors from generate_anchors(16,[0.5,1,2],[8,16,32]).
// ws=[23,16,11], hs=round(ws*ratios)=round([11.5,16,22])=[12,16,22]  (half-even)
__device__ __constant__ float ANC[9][4] = {
    {-84.f,  -40.f,  99.f,  55.f},   // r=0.5 s=8   (184x96)
    {-176.f, -88.f, 191.f, 103.f},   // r=0.5 s=16  (368x192)
    {-360.f,-184.f, 375.f, 199.f},   // r=0.5 s=32  (736x384)
    {-56.f,  -56.f,  71.f,  71.f},   // r=1   s=8   (128x128)
    {-120.f,-120.f, 135.f, 135.f},   // r=1   s=16  (256x256)
    {-248.f,-248.f, 263.f, 263.f},   // r=1   s=32  (512x512)
    {-36.f,  -80.f,  51.f,  95.f},   // r=2   s=8   (88x176)
    {-80.f, -168.f,  95.f, 183.f},   // r=2   s=16  (176x352)
    {-168.f,-344.f, 183.f, 359.f}};  // r=2   s=32  (352x704)

__device__ __forceinline__ uint32_t fkey(float s) {
    uint32_t u = __float_as_uint(s);
    return (u & 0x80000000u) ? ~u : (u | 0x80000000u);  // monotone: bigger float -> bigger key
}

// ---- K1: per-batch histogram of top-14 bits of score key --------------------
__global__ void k_hist(const float* __restrict__ scores, uint32_t* __restrict__ hist) {
    int gid = blockIdx.x * blockDim.x + threadIdx.x;
    if (gid >= B_NUM * NPER) return;
    int b = gid / NPER;
    int r = gid - b * NPER;
    int a = r / HWSZ;
    int p = r - a * HWSZ;
    float s = scores[(size_t)(b * 18 + 9 + a) * HWSZ + p];
    atomicAdd(&hist[b * NBINS + (fkey(s) >> 18)], 1u);
}

// ---- K2: find per-batch threshold bin (cum-from-top >= 6000) ----------------
__global__ void k_scan(const uint32_t* __restrict__ hist, uint32_t* __restrict__ thr) {
    int b = blockIdx.x;
    int tid = threadIdx.x;  // 256
    __shared__ uint32_t sh[256];
    __shared__ int done;
    __shared__ uint32_t cum;
    __shared__ int best;
    if (tid == 0) { done = 0; cum = 0; }
    __syncthreads();
    for (int base = NBINS - 256; base >= 0; base -= 256) {
        if (done) break;
        sh[tid] = hist[b * NBINS + base + tid];
        __syncthreads();
        // suffix (from-top) inclusive sums
        for (int off = 1; off < 256; off <<= 1) {
            uint32_t add = (tid + off < 256) ? sh[tid + off] : 0u;
            __syncthreads();
            sh[tid] += add;
            __syncthreads();
        }
        uint32_t total = sh[0];
        if (cum + total >= PRE_NMS) {
            if (tid == 0) best = -1;
            __syncthreads();
            if (cum + sh[tid] >= PRE_NMS) atomicMax(&best, base + tid);
            __syncthreads();
            if (tid == 0) { thr[b] = (uint32_t)best; done = 1; }
        } else if (tid == 0) {
            cum += total;
        }
        __syncthreads();
    }
    if (tid == 0 && !done) thr[b] = 0;
}

// ---- K3: compact candidates >= threshold bin --------------------------------
__global__ void k_compact(const float* __restrict__ scores, const uint32_t* __restrict__ thr,
                          uint32_t* __restrict__ cnt, uint64_t* __restrict__ cand) {
    int gid = blockIdx.x * blockDim.x + threadIdx.x;
    if (gid >= B_NUM * NPER) return;
    int b = gid / NPER;
    int r = gid - b * NPER;
    int a = r / HWSZ;
    int p = r - a * HWSZ;
    float s = scores[(size_t)(b * 18 + 9 + a) * HWSZ + p];
    uint32_t k = fkey(s);
    if ((k >> 18) >= thr[b]) {
        uint32_t pos = atomicAdd(&cnt[b], 1u);
        if (pos < CAND_CAP) {
            uint32_t idx = (uint32_t)(p * A_NUM + a);
            // ascending sort key: smaller = better score; ties -> smaller idx first
            cand[(size_t)b * CAND_CAP + pos] = ((uint64_t)(~k) << 32) | (uint64_t)idx;
        }
    }
}

// ---- K4: per-batch bitonic sort (8192, 64KB LDS) + decode top-6000 ----------
__global__ __launch_bounds__(1024) void k_sort_decode(
        const uint64_t* __restrict__ cand, const uint32_t* __restrict__ cnt,
        const float* __restrict__ deltas, const float* __restrict__ im_info,
        float4* __restrict__ boxes) {
    __shared__ uint64_t s[CAND_CAP];
    int b = blockIdx.x, tid = threadIdx.x;
    int m = (int)min(cnt[b], (uint32_t)CAND_CAP);
    for (int i = tid; i < CAND_CAP; i += 1024)
        s[i] = (i < m) ? cand[(size_t)b * CAND_CAP + i] : ~0ull;
    __syncthreads();
    for (unsigned k = 2; k <= CAND_CAP; k <<= 1) {
        for (unsigned j = k >> 1; j; j >>= 1) {
            for (unsigned p = tid; p < CAND_CAP / 2; p += 1024) {
                unsigned i = ((p & ~(j - 1)) << 1) | (p & (j - 1));
                unsigned ixj = i | j;
                uint64_t x = s[i], y = s[ixj];
                bool up = ((i & k) == 0);
                bool sw = up ? (x > y) : (x < y);
                if (sw) { s[i] = y; s[ixj] = x; }
            }
            __syncthreads();
        }
    }
    float him = im_info[b * 3 + 0], wim = im_info[b * 3 + 1];
    float ymax = __fsub_rn(him, 1.0f), xmax = __fsub_rn(wim, 1.0f);
    for (int r0 = tid; r0 < PRE_NMS; r0 += 1024) {
        uint32_t idx = (uint32_t)s[r0];
        float4 bx = make_float4(0.f, 0.f, 0.f, 0.f);
        if (idx < NPER) {
            int a = idx % A_NUM;
            int p = idx / A_NUM;
            int wc = p % W_FEAT, hr = p / W_FEAT;
            float ax1 = ANC[a][0] + (float)(wc * 16);
            float ay1 = ANC[a][1] + (float)(hr * 16);
            float ax2 = ANC[a][2] + (float)(wc * 16);
            float ay2 = ANC[a][3] + (float)(hr * 16);
            const float* dp = deltas + (size_t)(b * 36 + a * 4) * HWSZ + p;
            float dx = dp[0], dy = dp[HWSZ], dw = dp[2 * HWSZ], dh = dp[3 * HWSZ];
            // mirror numpy op-order; block FMA contraction with _rn intrinsics
            float ww = __fadd_rn(__fsub_rn(ax2, ax1), 1.0f);
            float hh = __fadd_rn(__fsub_rn(ay2, ay1), 1.0f);
            float cx = __fadd_rn(ax1, __fmul_rn(0.5f, ww));
            float cy = __fadd_rn(ay1, __fmul_rn(0.5f, hh));
            float pcx = __fadd_rn(__fmul_rn(dx, ww), cx);
            float pcy = __fadd_rn(__fmul_rn(dy, hh), cy);
            float ew = (float)exp((double)dw);   // ~correctly-rounded f32 exp
            float eh = (float)exp((double)dh);
            float pw = __fmul_rn(ew, ww);
            float ph = __fmul_rn(eh, hh);
            float x1 = __fsub_rn(pcx, __fmul_rn(0.5f, pw));
            float y1 = __fsub_rn(pcy, __fmul_rn(0.5f, ph));
            float x2 = __fadd_rn(pcx, __fmul_rn(0.5f, pw));
            float y2 = __fadd_rn(pcy, __fmul_rn(0.5f, ph));
            bx.x = fminf(fmaxf(x1, 0.0f), xmax);
            bx.y = fminf(fmaxf(y1, 0.0f), ymax);
            bx.z = fminf(fmaxf(x2, 0.0f), xmax);
            bx.w = fminf(fmaxf(y2, 0.0f), ymax);
        }
        boxes[(size_t)b * PRE_NMS + r0] = bx;
    }
}

// ---- K5: greedy NMS, one wave per batch -------------------------------------
__global__ __launch_bounds__(64) void k_nms(const float4* __restrict__ boxes,
                                            float* __restrict__ out) {
    int b = blockIdx.x, lane = threadIdx.x;
    __shared__ float4 kbox[POST_NMS];
    __shared__ float karea[POST_NMS];
    const float4* bb = boxes + (size_t)b * PRE_NMS;
    int K = 0;
    for (int r = 0; r < PRE_NMS; ++r) {
        float4 c = bb[r];
        float ca = __fmul_rn(__fadd_rn(__fsub_rn(c.z, c.x), 1.0f),
                             __fadd_rn(__fsub_rn(c.w, c.y), 1.0f));
        bool viol = false;
        for (int k = lane; k < K; k += 64) {
            float4 q = kbox[k];
            float xx1 = fmaxf(q.x, c.x);
            float yy1 = fmaxf(q.y, c.y);
            float xx2 = fminf(q.z, c.z);
            float yy2 = fminf(q.w, c.w);
            float iw = fmaxf(0.0f, __fadd_rn(__fsub_rn(xx2, xx1), 1.0f));
            float ih = fmaxf(0.0f, __fadd_rn(__fsub_rn(yy2, yy1), 1.0f));
            float inter = __fmul_rn(iw, ih);
            float den = __fsub_rn(__fadd_rn(karea[k], ca), inter);
            float iou = __fdiv_rn(inter, den);
            viol |= (iou > 0.7f);
        }
        if (!__any((int)viol)) {
            if (lane == 0) {
                kbox[K] = c;
                karea[K] = ca;
                float* o = out + (size_t)(b * POST_NMS + K) * 5;
                o[0] = (float)b; o[1] = c.x; o[2] = c.y; o[3] = c.z; o[4] = c.w;
            }
            K++;
        }
        __syncthreads();
        if (K >= POST_NMS) break;
    }
    for (int rr = K + lane; rr < POST_NMS; rr += 64) {
        float* o = out + (size_t)(b * POST_NMS + rr) * 5;
        o[0] = (float)b; o[1] = 0.f; o[2] = 0.f; o[3] = 0.f; o[4] = 0.f;
    }
}

extern "C" void kernel_launch(void* const* d_in, const int* in_sizes, int n_in,
                              void* d_out, int out_size, void* d_ws, size_t ws_size,
                              hipStream_t stream) {
    const float* scores  = (const float*)d_in[0];
    const float* deltas  = (const float*)d_in[1];
    const float* im_info = (const float*)d_in[2];
    float* out = (float*)d_out;
    char* ws = (char*)d_ws;

    uint32_t* hist = (uint32_t*)(ws);                 // 16*16384*4 = 1,048,576
    uint32_t* cnt  = (uint32_t*)(ws + 1048576);       // 64
    uint32_t* thr  = (uint32_t*)(ws + 1048640);       // 64
    uint64_t* cand = (uint64_t*)(ws + 1048704);       // 16*8192*8 = 1,048,576
    float4*   boxes= (float4*)  (ws + 2097280);       // 16*6000*16 = 1,536,000

    hipMemsetAsync(ws, 0, 1048640, stream);           // hist + cnt

    int total = B_NUM * NPER;
    k_hist<<<(total + 255) / 256, 256, 0, stream>>>(scores, hist);
    k_scan<<<B_NUM, 256, 0, stream>>>(hist, thr);
    k_compact<<<(total + 255) / 256, 256, 0, stream>>>(scores, thr, cnt, cand);
    k_sort_decode<<<B_NUM, 1024, 0, stream>>>(cand, cnt, deltas, im_info, boxes);
    k_nms<<<B_NUM, 64, 0, stream>>>(boxes, out);
}

// Round 3
// 600.311 us; speedup vs baseline: 3.4431x; 3.4431x over previous
//
#include <hip/hip_runtime.h>
#include <cstdint>
#include <cmath>

#define HWSZ    15000      // H*W = 100*150
#define W_FEAT  150
#define A_NUM   9
#define NPER    135000     // A_NUM * HWSZ
#define B_NUM   16
#define PRE_NMS 6000
#define POST_NMS 300
#define NBINS   16384      // top-14-bit histogram
#define CAND_CAP 8192

// 9 base anchors from generate_anchors(16,[0.5,1,2],[8,16,32]).
// ws=[23,16,11], hs=round(ws*ratios)=round([11.5,16,22])=[12,16,22]  (half-even)
__device__ __constant__ float ANC[9][4] = {
    {-84.f,  -40.f,  99.f,  55.f},   // r=0.5 s=8   (184x96)
    {-176.f, -88.f, 191.f, 103.f},   // r=0.5 s=16  (368x192)
    {-360.f,-184.f, 375.f, 199.f},   // r=0.5 s=32  (736x384)
    {-56.f,  -56.f,  71.f,  71.f},   // r=1   s=8   (128x128)
    {-120.f,-120.f, 135.f, 135.f},   // r=1   s=16  (256x256)
    {-248.f,-248.f, 263.f, 263.f},   // r=1   s=32  (512x512)
    {-36.f,  -80.f,  51.f,  95.f},   // r=2   s=8   (88x176)
    {-80.f, -168.f,  95.f, 183.f},   // r=2   s=16  (176x352)
    {-168.f,-344.f, 183.f, 359.f}};  // r=2   s=32  (352x704)

__device__ __forceinline__ uint32_t fkey(float s) {
    uint32_t u = __float_as_uint(s);
    return (u & 0x80000000u) ? ~u : (u | 0x80000000u);  // monotone: bigger float -> bigger key
}

// ---- K1: per-batch histogram of top-14 bits of score key --------------------
__global__ void k_hist(const float* __restrict__ scores, uint32_t* __restrict__ hist) {
    int b = blockIdx.y;
    int r = blockIdx.x * blockDim.x + threadIdx.x;
    if (r >= NPER) return;
    int a = r / HWSZ;
    int p = r - a * HWSZ;
    float s = scores[(size_t)(b * 18 + 9 + a) * HWSZ + p];
    atomicAdd(&hist[b * NBINS + (fkey(s) >> 18)], 1u);
}

// ---- K2: find per-batch threshold bin (cum-from-top >= 6000) ----------------
__global__ void k_scan(const uint32_t* __restrict__ hist, uint32_t* __restrict__ thr) {
    int b = blockIdx.x;
    int tid = threadIdx.x;  // 256
    __shared__ uint32_t sh[256];
    __shared__ int done;
    __shared__ uint32_t cum;
    __shared__ int best;
    if (tid == 0) { done = 0; cum = 0; }
    __syncthreads();
    for (int base = NBINS - 256; base >= 0; base -= 256) {
        if (done) break;
        sh[tid] = hist[b * NBINS + base + tid];
        __syncthreads();
        // suffix (from-top) inclusive sums
        for (int off = 1; off < 256; off <<= 1) {
            uint32_t add = (tid + off < 256) ? sh[tid + off] : 0u;
            __syncthreads();
            sh[tid] += add;
            __syncthreads();
        }
        uint32_t total = sh[0];
        if (cum + total >= PRE_NMS) {
            if (tid == 0) best = -1;
            __syncthreads();
            if (cum + sh[tid] >= PRE_NMS) atomicMax(&best, base + tid);
            __syncthreads();
            if (tid == 0) { thr[b] = (uint32_t)best; done = 1; }
        } else if (tid == 0) {
            cum += total;
        }
        __syncthreads();
    }
    if (tid == 0 && !done) thr[b] = 0;
}

// ---- K3: compact candidates >= threshold bin (two-level aggregation) --------
__global__ void k_compact(const float* __restrict__ scores, const uint32_t* __restrict__ thr,
                          uint32_t* __restrict__ cnt, uint64_t* __restrict__ cand) {
    int b = blockIdx.y;
    int r = blockIdx.x * blockDim.x + threadIdx.x;
    __shared__ uint32_t lcnt, lbase;
    if (threadIdx.x == 0) lcnt = 0;
    __syncthreads();
    bool win = false;
    uint32_t pos = 0, k = 0, idx = 0;
    if (r < NPER) {
        int a = r / HWSZ;
        int p = r - a * HWSZ;
        float s = scores[(size_t)(b * 18 + 9 + a) * HWSZ + p];
        k = fkey(s);
        if ((k >> 18) >= thr[b]) {
            win = true;
            pos = atomicAdd(&lcnt, 1u);     // LDS atomic: cheap
            idx = (uint32_t)(p * A_NUM + a);
        }
    }
    __syncthreads();
    if (threadIdx.x == 0 && lcnt)
        lbase = atomicAdd(&cnt[b], lcnt);   // ONE global atomic per block
    __syncthreads();
    if (win) {
        uint32_t g = lbase + pos;
        if (g < CAND_CAP)
            cand[(size_t)b * CAND_CAP + g] = ((uint64_t)(~k) << 32) | (uint64_t)idx;
    }
}

// ---- K4: per-batch bitonic sort (8192, 64KB LDS) + decode top-6000 ----------
__global__ __launch_bounds__(1024) void k_sort_decode(
        const uint64_t* __restrict__ cand, const uint32_t* __restrict__ cnt,
        const float* __restrict__ deltas, const float* __restrict__ im_info,
        float4* __restrict__ boxes) {
    __shared__ uint64_t s[CAND_CAP];
    int b = blockIdx.x, tid = threadIdx.x;
    int m = (int)min(cnt[b], (uint32_t)CAND_CAP);
    for (int i = tid; i < CAND_CAP; i += 1024)
        s[i] = (i < m) ? cand[(size_t)b * CAND_CAP + i] : ~0ull;
    __syncthreads();
    for (unsigned k = 2; k <= CAND_CAP; k <<= 1) {
        for (unsigned j = k >> 1; j; j >>= 1) {
            for (unsigned p = tid; p < CAND_CAP / 2; p += 1024) {
                unsigned i = ((p & ~(j - 1)) << 1) | (p & (j - 1));
                unsigned ixj = i | j;
                uint64_t x = s[i], y = s[ixj];
                bool up = ((i & k) == 0);
                bool sw = up ? (x > y) : (x < y);
                if (sw) { s[i] = y; s[ixj] = x; }
            }
            __syncthreads();
        }
    }
    float him = im_info[b * 3 + 0], wim = im_info[b * 3 + 1];
    float ymax = __fsub_rn(him, 1.0f), xmax = __fsub_rn(wim, 1.0f);
    for (int r0 = tid; r0 < PRE_NMS; r0 += 1024) {
        uint32_t idx = (uint32_t)s[r0];
        float4 bx = make_float4(0.f, 0.f, 0.f, 0.f);
        if (idx < NPER) {
            int a = idx % A_NUM;
            int p = idx / A_NUM;
            int wc = p % W_FEAT, hr = p / W_FEAT;
            float ax1 = ANC[a][0] + (float)(wc * 16);
            float ay1 = ANC[a][1] + (float)(hr * 16);
            float ax2 = ANC[a][2] + (float)(wc * 16);
            float ay2 = ANC[a][3] + (float)(hr * 16);
            const float* dp = deltas + (size_t)(b * 36 + a * 4) * HWSZ + p;
            float dx = dp[0], dy = dp[HWSZ], dw = dp[2 * HWSZ], dh = dp[3 * HWSZ];
            // mirror numpy op-order; block FMA contraction with _rn intrinsics
            float ww = __fadd_rn(__fsub_rn(ax2, ax1), 1.0f);
            float hh = __fadd_rn(__fsub_rn(ay2, ay1), 1.0f);
            float cx = __fadd_rn(ax1, __fmul_rn(0.5f, ww));
            float cy = __fadd_rn(ay1, __fmul_rn(0.5f, hh));
            float pcx = __fadd_rn(__fmul_rn(dx, ww), cx);
            float pcy = __fadd_rn(__fmul_rn(dy, hh), cy);
            float ew = (float)exp((double)dw);   // ~correctly-rounded f32 exp
            float eh = (float)exp((double)dh);
            float pw = __fmul_rn(ew, ww);
            float ph = __fmul_rn(eh, hh);
            float x1 = __fsub_rn(pcx, __fmul_rn(0.5f, pw));
            float y1 = __fsub_rn(pcy, __fmul_rn(0.5f, ph));
            float x2 = __fadd_rn(pcx, __fmul_rn(0.5f, pw));
            float y2 = __fadd_rn(pcy, __fmul_rn(0.5f, ph));
            bx.x = fminf(fmaxf(x1, 0.0f), xmax);
            bx.y = fminf(fmaxf(y1, 0.0f), ymax);
            bx.z = fminf(fmaxf(x2, 0.0f), xmax);
            bx.w = fminf(fmaxf(y2, 0.0f), ymax);
        }
        boxes[(size_t)b * PRE_NMS + r0] = bx;
    }
}

// ---- K5: greedy NMS, one wave per batch -------------------------------------
__global__ __launch_bounds__(64) void k_nms(const float4* __restrict__ boxes,
                                            float* __restrict__ out) {
    int b = blockIdx.x, lane = threadIdx.x;
    __shared__ float4 kbox[POST_NMS];
    __shared__ float karea[POST_NMS];
    const float4* bb = boxes + (size_t)b * PRE_NMS;
    int K = 0;
    for (int r = 0; r < PRE_NMS; ++r) {
        float4 c = bb[r];
        float ca = __fmul_rn(__fadd_rn(__fsub_rn(c.z, c.x), 1.0f),
                             __fadd_rn(__fsub_rn(c.w, c.y), 1.0f));
        bool viol = false;
        for (int k = lane; k < K; k += 64) {
            float4 q = kbox[k];
            float xx1 = fmaxf(q.x, c.x);
            float yy1 = fmaxf(q.y, c.y);
            float xx2 = fminf(q.z, c.z);
            float yy2 = fminf(q.w, c.w);
            float iw = fmaxf(0.0f, __fadd_rn(__fsub_rn(xx2, xx1), 1.0f));
            float ih = fmaxf(0.0f, __fadd_rn(__fsub_rn(yy2, yy1), 1.0f));
            float inter = __fmul_rn(iw, ih);
            float den = __fsub_rn(__fadd_rn(karea[k], ca), inter);
            float iou = __fdiv_rn(inter, den);
            viol |= (iou > 0.7f);
        }
        if (!__any((int)viol)) {
            if (lane == 0) {
                kbox[K] = c;
                karea[K] = ca;
                float* o = out + (size_t)(b * POST_NMS + K) * 5;
                o[0] = (float)b; o[1] = c.x; o[2] = c.y; o[3] = c.z; o[4] = c.w;
            }
            K++;
        }
        __syncthreads();
        if (K >= POST_NMS) break;
    }
    for (int rr = K + lane; rr < POST_NMS; rr += 64) {
        float* o = out + (size_t)(b * POST_NMS + rr) * 5;
        o[0] = (float)b; o[1] = 0.f; o[2] = 0.f; o[3] = 0.f; o[4] = 0.f;
    }
}

extern "C" void kernel_launch(void* const* d_in, const int* in_sizes, int n_in,
                              void* d_out, int out_size, void* d_ws, size_t ws_size,
                              hipStream_t stream) {
    const float* scores  = (const float*)d_in[0];
    const float* deltas  = (const float*)d_in[1];
    const float* im_info = (const float*)d_in[2];
    float* out = (float*)d_out;
    char* ws = (char*)d_ws;

    uint32_t* hist = (uint32_t*)(ws);                 // 16*16384*4 = 1,048,576
    uint32_t* cnt  = (uint32_t*)(ws + 1048576);       // 64
    uint32_t* thr  = (uint32_t*)(ws + 1048640);       // 64
    uint64_t* cand = (uint64_t*)(ws + 1048704);       // 16*8192*8 = 1,048,576
    float4*   boxes= (float4*)  (ws + 2097280);       // 16*6000*16 = 1,536,000

    hipMemsetAsync(ws, 0, 1048640, stream);           // hist + cnt

    dim3 grid2d((NPER + 255) / 256, B_NUM);
    k_hist<<<grid2d, 256, 0, stream>>>(scores, hist);
    k_scan<<<B_NUM, 256, 0, stream>>>(hist, thr);
    k_compact<<<grid2d, 256, 0, stream>>>(scores, thr, cnt, cand);
    k_sort_decode<<<B_NUM, 1024, 0, stream>>>(cand, cnt, deltas, im_info, boxes);
    k_nms<<<B_NUM, 64, 0, stream>>>(boxes, out);
}